// Round 1
// baseline (97.807 us; speedup 1.0000x reference)
//
#include <hip/hip_runtime.h>
#include <math.h>

#define N_PTS 2048
#define N_SETS 16          // B*S = 2*8
#define B_VAL 2.0f
#define BLOCK 256

__device__ __forceinline__ float sl1(float d) {
    d = fabsf(d);
    return d < 1.0f ? 0.5f * d * d : d - 0.5f;
}

__global__ void init_out_kernel(float* out) {
    out[0] = 0.0f;
    out[1] = 0.0f;
}

// One block = 256 query points of one (set, direction).
// grid = (8 chunks, 16 sets, 2 directions), block = 256.
// dir 0: queries = X_v, candidates = target_X_v  (tmp1)
// dir 1: queries = target_X_v, candidates = X_v  (tmp2)
__global__ __launch_bounds__(BLOCK) void chamfer_kernel(
    const float* __restrict__ X, const float* __restrict__ T,
    const float* __restrict__ W, float* __restrict__ out)
{
    const int chunk = blockIdx.x;
    const int set   = blockIdx.y;
    const int dir   = blockIdx.z;

    const float* qsrc = (dir == 0) ? (T + (size_t)set * N_PTS * 3)
                                   : (X + (size_t)set * N_PTS * 3);
    const float* psrc = (dir == 0) ? (X + (size_t)set * N_PTS * 3)
                                   : (T + (size_t)set * N_PTS * 3);

    __shared__ float qx[N_PTS];
    __shared__ float qy[N_PTS];
    __shared__ float qz[N_PTS];
    __shared__ float q2[N_PTS];
    __shared__ float wpart[4];

    const int tid = threadIdx.x;

    // Coalesced staging of candidate points: flat read, scatter to SoA.
    for (int j = tid; j < N_PTS * 3; j += BLOCK) {
        float v = qsrc[j];
        int pt = j / 3;
        int d  = j - pt * 3;
        if (d == 0) qx[pt] = v;
        else if (d == 1) qy[pt] = v;
        else qz[pt] = v;
    }
    __syncthreads();
    for (int i = tid; i < N_PTS; i += BLOCK) {
        float a = qx[i], b = qy[i], c = qz[i];
        q2[i] = a * a + b * b + c * c;
    }
    __syncthreads();

    // My query point.
    const int n = chunk * BLOCK + tid;
    const float px = psrc[n * 3 + 0];
    const float py = psrc[n * 3 + 1];
    const float pz = psrc[n * 3 + 2];
    // argmin_m (p2 + q2[m] - 2 p.q[m])  ==  argmin_m (q2[m] - 2 p.q[m])
    const float px2 = -2.0f * px;
    const float py2 = -2.0f * py;
    const float pz2 = -2.0f * pz;

    // 4 independent argmin chains over m = 4*k + j to break the serial
    // cmp->select dependency (we only have ~1 wave/SIMD).
    float b0 = INFINITY, b1 = INFINITY, b2 = INFINITY, b3 = INFINITY;
    int   i0 = 0, i1 = 0, i2 = 0, i3 = 0;  // store m4; global idx = 4*m4+j

    const float4* qx4 = reinterpret_cast<const float4*>(qx);
    const float4* qy4 = reinterpret_cast<const float4*>(qy);
    const float4* qz4 = reinterpret_cast<const float4*>(qz);
    const float4* q24 = reinterpret_cast<const float4*>(q2);

#pragma unroll 4
    for (int m4 = 0; m4 < N_PTS / 4; ++m4) {
        float4 vx = qx4[m4];
        float4 vy = qy4[m4];
        float4 vz = qz4[m4];
        float4 vh = q24[m4];
        float d0 = fmaf(px2, vx.x, fmaf(py2, vy.x, fmaf(pz2, vz.x, vh.x)));
        float d1 = fmaf(px2, vx.y, fmaf(py2, vy.y, fmaf(pz2, vz.y, vh.y)));
        float d2 = fmaf(px2, vx.z, fmaf(py2, vy.z, fmaf(pz2, vz.z, vh.z)));
        float d3 = fmaf(px2, vx.w, fmaf(py2, vy.w, fmaf(pz2, vz.w, vh.w)));
        if (d0 < b0) { b0 = d0; i0 = m4; }
        if (d1 < b1) { b1 = d1; i1 = m4; }
        if (d2 < b2) { b2 = d2; i2 = m4; }
        if (d3 < b3) { b3 = d3; i3 = m4; }
    }

    // Merge chains with first-occurrence (lowest global index) tiebreak.
    float bb = b0; int bi = i0 * 4 + 0;
    {
        int g1 = i1 * 4 + 1;
        if (b1 < bb || (b1 == bb && g1 < bi)) { bb = b1; bi = g1; }
        int g2 = i2 * 4 + 2;
        if (b2 < bb || (b2 == bb && g2 < bi)) { bb = b2; bi = g2; }
        int g3 = i3 * 4 + 3;
        if (b3 < bb || (b3 == bb && g3 < bi)) { bb = b3; bi = g3; }
    }

    // Smooth-L1 vs nearest candidate, summed over 3 dims.
    float s = sl1(px - qx[bi]) + sl1(py - qy[bi]) + sl1(pz - qz[bi]);

    // Block reduction: wave shuffle then cross-wave via LDS.
    for (int off = 32; off > 0; off >>= 1)
        s += __shfl_down(s, off, 64);
    if ((tid & 63) == 0) wpart[tid >> 6] = s;
    __syncthreads();
    if (tid == 0) {
        float tot = wpart[0] + wpart[1] + wpart[2] + wpart[3];
        // mean over (N,3) then weighted sum over sets, / B
        atomicAdd(&out[0], W[set] * tot * (1.0f / (N_PTS * 3.0f * B_VAL)));
    }
}

// Centroid loss: one block per set.
__global__ __launch_bounds__(BLOCK) void centroid_kernel(
    const float* __restrict__ X, const float* __restrict__ T,
    float* __restrict__ out)
{
    const int set = blockIdx.x;
    const int tid = threadIdx.x;
    const float* xb = X + (size_t)set * N_PTS * 3;
    const float* tb = T + (size_t)set * N_PTS * 3;

    float acc[6] = {0, 0, 0, 0, 0, 0};
    for (int i = tid; i < N_PTS; i += BLOCK) {
        acc[0] += xb[i * 3 + 0];
        acc[1] += xb[i * 3 + 1];
        acc[2] += xb[i * 3 + 2];
        acc[3] += tb[i * 3 + 0];
        acc[4] += tb[i * 3 + 1];
        acc[5] += tb[i * 3 + 2];
    }

    __shared__ float red[6][BLOCK];
    for (int k = 0; k < 6; ++k) red[k][tid] = acc[k];
    __syncthreads();
    for (int sft = BLOCK / 2; sft > 0; sft >>= 1) {
        if (tid < sft)
            for (int k = 0; k < 6; ++k) red[k][tid] += red[k][tid + sft];
        __syncthreads();
    }
    if (tid == 0) {
        const float inv = 1.0f / (float)N_PTS;
        float l = sl1(red[0][0] * inv - red[3][0] * inv)
                + sl1(red[1][0] * inv - red[4][0] * inv)
                + sl1(red[2][0] * inv - red[5][0] * inv);
        atomicAdd(&out[1], l * (1.0f / (B_VAL * 3.0f)));
    }
}

extern "C" void kernel_launch(void* const* d_in, const int* in_sizes, int n_in,
                              void* d_out, int out_size, void* d_ws, size_t ws_size,
                              hipStream_t stream) {
    const float* X = (const float*)d_in[0];
    const float* T = (const float*)d_in[1];
    const float* W = (const float*)d_in[2];
    float* out = (float*)d_out;

    init_out_kernel<<<1, 1, 0, stream>>>(out);
    centroid_kernel<<<N_SETS, BLOCK, 0, stream>>>(X, T, out);
    chamfer_kernel<<<dim3(N_PTS / BLOCK, N_SETS, 2), BLOCK, 0, stream>>>(X, T, W, out);
}

// Round 2
// 89.037 us; speedup vs baseline: 1.0985x; 1.0985x over previous
//
#include <hip/hip_runtime.h>
#include <math.h>

#define N_PTS 2048
#define N_SETS 16          // B*S = 2*8
#define B_VAL 2.0f
#define BLOCK 256
#define SEGS 16
#define CPS (N_PTS / SEGS)   // 128 candidates per segment
#define QPT 8                // queries per thread

__device__ __forceinline__ float sl1(float d) {
    d = fabsf(d);
    return d < 1.0f ? 0.5f * d * d : d - 0.5f;
}

// Order-preserving float -> uint32 (finite values).
__device__ __forceinline__ unsigned int fkey(float f) {
    unsigned int b = __float_as_uint(f);
    return (b & 0x80000000u) ? ~b : (b | 0x80000000u);
}

// grid = (SEGS, N_SETS, 2). Each block: ALL 2048 queries of one (set,dir)
// against a 128-candidate segment. Thread t handles queries t+256*j.
// Partial argmin -> packed (key,idx) atomicMin into ws[(set*2+dir)*2048+q].
__global__ __launch_bounds__(BLOCK) void chamfer_partial(
    const float* __restrict__ X, const float* __restrict__ T,
    unsigned long long* __restrict__ ws, float* __restrict__ out)
{
    const int seg = blockIdx.x;
    const int set = blockIdx.y;
    const int dir = blockIdx.z;
    const int tid = threadIdx.x;

    if (seg == 0 && set == 0 && dir == 0 && tid == 0) {
        out[0] = 0.0f;  // zero before finalize/centroid atomics (stream order)
        out[1] = 0.0f;
    }

    const float* psrc = (dir == 0) ? (X + (size_t)set * N_PTS * 3)
                                   : (T + (size_t)set * N_PTS * 3);
    const float* csrc = (dir == 0) ? (T + (size_t)set * N_PTS * 3)
                                   : (X + (size_t)set * N_PTS * 3);

    // Stage this segment's candidates as (x,y,z,|c|^2) float4 in LDS.
    __shared__ float4 cand[CPS];
    if (tid < CPS) {
        const int g = seg * CPS + tid;
        float cx = csrc[g * 3 + 0];
        float cy = csrc[g * 3 + 1];
        float cz = csrc[g * 3 + 2];
        cand[tid] = make_float4(cx, cy, cz, cx * cx + cy * cy + cz * cz);
    }
    __syncthreads();

    // Load my 8 query points; precompute -2*coord (p^2 dropped: constant shift).
    float ax[QPT], ay[QPT], az[QPT];
    float best[QPT];
    int   bidx[QPT];
#pragma unroll
    for (int j = 0; j < QPT; ++j) {
        const int q = tid + BLOCK * j;
        ax[j] = -2.0f * psrc[q * 3 + 0];
        ay[j] = -2.0f * psrc[q * 3 + 1];
        az[j] = -2.0f * psrc[q * 3 + 2];
        best[j] = INFINITY;
        bidx[j] = 0;
    }

    // Inner loop: one broadcast LDS read amortized over 8 queries.
#pragma unroll 4
    for (int m = 0; m < CPS; ++m) {
        float4 c = cand[m];
#pragma unroll
        for (int j = 0; j < QPT; ++j) {
            float d = fmaf(ax[j], c.x, fmaf(ay[j], c.y, fmaf(az[j], c.z, c.w)));
            if (d < best[j]) { best[j] = d; bidx[j] = m; }
        }
    }

    // Publish partials. Tiebreak: equal keys -> lower global idx wins (low bits).
    unsigned long long* wq = ws + ((size_t)(set * 2 + dir) << 11);
#pragma unroll
    for (int j = 0; j < QPT; ++j) {
        const int q = tid + BLOCK * j;
        const unsigned int gidx = (unsigned int)(seg * CPS + bidx[j]);
        unsigned long long key = ((unsigned long long)fkey(best[j]) << 32) | gidx;
        atomicMin(&wq[q], key);
    }
}

// grid = (N_PTS/BLOCK, N_SETS, 2). Reads final argmin, computes smooth-L1,
// reduces, applies weights.
__global__ __launch_bounds__(BLOCK) void finalize_kernel(
    const float* __restrict__ X, const float* __restrict__ T,
    const float* __restrict__ W, const unsigned long long* __restrict__ ws,
    float* __restrict__ out)
{
    const int chunk = blockIdx.x;
    const int set   = blockIdx.y;
    const int dir   = blockIdx.z;
    const int tid   = threadIdx.x;
    const int n     = chunk * BLOCK + tid;

    const float* psrc = (dir == 0) ? (X + (size_t)set * N_PTS * 3)
                                   : (T + (size_t)set * N_PTS * 3);
    const float* csrc = (dir == 0) ? (T + (size_t)set * N_PTS * 3)
                                   : (X + (size_t)set * N_PTS * 3);

    const unsigned long long key = ws[((size_t)(set * 2 + dir) << 11) + n];
    const unsigned int idx = (unsigned int)(key & 0xFFFFFFFFu);

    float s = sl1(psrc[n * 3 + 0] - csrc[idx * 3 + 0])
            + sl1(psrc[n * 3 + 1] - csrc[idx * 3 + 1])
            + sl1(psrc[n * 3 + 2] - csrc[idx * 3 + 2]);

    // Block reduction: wave shuffle then cross-wave via LDS.
    __shared__ float wpart[4];
    for (int off = 32; off > 0; off >>= 1)
        s += __shfl_down(s, off, 64);
    if ((tid & 63) == 0) wpart[tid >> 6] = s;
    __syncthreads();
    if (tid == 0) {
        float tot = wpart[0] + wpart[1] + wpart[2] + wpart[3];
        atomicAdd(&out[0], W[set] * tot * (1.0f / (N_PTS * 3.0f * B_VAL)));
    }
}

// Centroid loss: one block per set, shuffle-based reduction.
__global__ __launch_bounds__(BLOCK) void centroid_kernel(
    const float* __restrict__ X, const float* __restrict__ T,
    float* __restrict__ out)
{
    const int set = blockIdx.x;
    const int tid = threadIdx.x;
    const float* xb = X + (size_t)set * N_PTS * 3;
    const float* tb = T + (size_t)set * N_PTS * 3;

    float acc[6] = {0, 0, 0, 0, 0, 0};
    for (int i = tid; i < N_PTS; i += BLOCK) {
        acc[0] += xb[i * 3 + 0];
        acc[1] += xb[i * 3 + 1];
        acc[2] += xb[i * 3 + 2];
        acc[3] += tb[i * 3 + 0];
        acc[4] += tb[i * 3 + 1];
        acc[5] += tb[i * 3 + 2];
    }

#pragma unroll
    for (int k = 0; k < 6; ++k)
        for (int off = 32; off > 0; off >>= 1)
            acc[k] += __shfl_down(acc[k], off, 64);

    __shared__ float red[4][6];
    if ((tid & 63) == 0)
#pragma unroll
        for (int k = 0; k < 6; ++k) red[tid >> 6][k] = acc[k];
    __syncthreads();
    if (tid == 0) {
        const float inv = 1.0f / (float)N_PTS;
        float l = 0.0f;
#pragma unroll
        for (int k = 0; k < 3; ++k) {
            float a = (red[0][k] + red[1][k] + red[2][k] + red[3][k]) * inv;
            float b = (red[0][k + 3] + red[1][k + 3] + red[2][k + 3] + red[3][k + 3]) * inv;
            l += sl1(a - b);
        }
        atomicAdd(&out[1], l * (1.0f / (B_VAL * 3.0f)));
    }
}

extern "C" void kernel_launch(void* const* d_in, const int* in_sizes, int n_in,
                              void* d_out, int out_size, void* d_ws, size_t ws_size,
                              hipStream_t stream) {
    const float* X = (const float*)d_in[0];
    const float* T = (const float*)d_in[1];
    const float* W = (const float*)d_in[2];
    float* out = (float*)d_out;
    unsigned long long* ws = (unsigned long long*)d_ws;

    // ws: 32 * 2048 packed (key,idx) u64 = 512 KB. 0xFF.. == UINT64_MAX.
    hipMemsetAsync(d_ws, 0xFF, (size_t)N_SETS * 2 * N_PTS * sizeof(unsigned long long), stream);

    chamfer_partial<<<dim3(SEGS, N_SETS, 2), BLOCK, 0, stream>>>(X, T, ws, out);
    centroid_kernel<<<N_SETS, BLOCK, 0, stream>>>(X, T, out);
    finalize_kernel<<<dim3(N_PTS / BLOCK, N_SETS, 2), BLOCK, 0, stream>>>(X, T, W, ws, out);
}

// Round 3
// 86.477 us; speedup vs baseline: 1.1310x; 1.0296x over previous
//
#include <hip/hip_runtime.h>
#include <math.h>

#define N_PTS 2048
#define N_SETS 16          // B*S = 2*8
#define B_VAL 2.0f
#define BLOCK 256
#define SEGS 16
#define CPS (N_PTS / SEGS)   // 128 candidates per segment
#define QPT 8                // queries per thread (2048 / 256)

__device__ __forceinline__ float sl1(float d) {
    d = fabsf(d);
    return d < 1.0f ? 0.5f * d * d : d - 0.5f;
}

// grid = (SEGS, N_SETS, 2). Each block: ALL 2048 queries of one (set,dir)
// against a 128-candidate segment. Thread t handles queries t+256*j.
// Per-seg (dist, idx) written contention-free to ws[sd][seg][q].
__global__ __launch_bounds__(BLOCK) void chamfer_partial(
    const float* __restrict__ X, const float* __restrict__ T,
    float2* __restrict__ ws, float* __restrict__ out)
{
    const int seg = blockIdx.x;
    const int set = blockIdx.y;
    const int dir = blockIdx.z;
    const int tid = threadIdx.x;

    if (seg == 0 && set == 0 && dir == 0 && tid == 0) {
        out[0] = 0.0f;  // consumed by the NEXT kernel (stream-ordered)
        out[1] = 0.0f;
    }

    const float* psrc = (dir == 0) ? (X + (size_t)set * N_PTS * 3)
                                   : (T + (size_t)set * N_PTS * 3);
    const float* csrc = (dir == 0) ? (T + (size_t)set * N_PTS * 3)
                                   : (X + (size_t)set * N_PTS * 3);

    // Stage this segment's candidates as (x,y,z,|c|^2) float4 in LDS.
    __shared__ float4 cand[CPS];
    if (tid < CPS) {
        const int g = seg * CPS + tid;
        float cx = csrc[g * 3 + 0];
        float cy = csrc[g * 3 + 1];
        float cz = csrc[g * 3 + 2];
        cand[tid] = make_float4(cx, cy, cz, cx * cx + cy * cy + cz * cz);
    }
    __syncthreads();

    // My 8 query points; precompute -2*coord (p^2 dropped: constant shift).
    float ax[QPT], ay[QPT], az[QPT];
    float best[QPT];
    int   bidx[QPT];
#pragma unroll
    for (int j = 0; j < QPT; ++j) {
        const int q = tid + BLOCK * j;
        ax[j] = -2.0f * psrc[q * 3 + 0];
        ay[j] = -2.0f * psrc[q * 3 + 1];
        az[j] = -2.0f * psrc[q * 3 + 2];
        best[j] = INFINITY;
        bidx[j] = 0;
    }

    // One broadcast LDS read amortized over 8 queries (48 VALU / ds_read).
#pragma unroll 4
    for (int m = 0; m < CPS; ++m) {
        float4 c = cand[m];
#pragma unroll
        for (int j = 0; j < QPT; ++j) {
            float d = fmaf(ax[j], c.x, fmaf(ay[j], c.y, fmaf(az[j], c.z, c.w)));
            if (d < best[j]) { best[j] = d; bidx[j] = m; }  // strict <: first occurrence
        }
    }

    // Contention-free coalesced stores: ws[(sd*SEGS+seg)*2048 + q].
    float2* wq = ws + ((size_t)((set * 2 + dir) * SEGS + seg) << 11);
#pragma unroll
    for (int j = 0; j < QPT; ++j) {
        const int q = tid + BLOCK * j;
        float2 v;
        v.x = best[j];
        v.y = __uint_as_float((unsigned int)(seg * CPS + bidx[j]));
        wq[q] = v;
    }
}

// grid = (N_PTS/BLOCK + 1, N_SETS, 2).
// chunk < 8 : merge 16 seg-results per query, smooth-L1, weighted reduce.
// chunk == 8, dir == 0 : centroid loss for this set. (dir==1: idle)
__global__ __launch_bounds__(BLOCK) void finalize_kernel(
    const float* __restrict__ X, const float* __restrict__ T,
    const float* __restrict__ W, const float2* __restrict__ ws,
    float* __restrict__ out)
{
    const int chunk = blockIdx.x;
    const int set   = blockIdx.y;
    const int dir   = blockIdx.z;
    const int tid   = threadIdx.x;

    if (chunk == N_PTS / BLOCK) {
        // ---- centroid path ----
        if (dir != 0) return;
        const float* xb = X + (size_t)set * N_PTS * 3;
        const float* tb = T + (size_t)set * N_PTS * 3;
        float acc[6] = {0, 0, 0, 0, 0, 0};
        for (int i = tid; i < N_PTS; i += BLOCK) {
            acc[0] += xb[i * 3 + 0];
            acc[1] += xb[i * 3 + 1];
            acc[2] += xb[i * 3 + 2];
            acc[3] += tb[i * 3 + 0];
            acc[4] += tb[i * 3 + 1];
            acc[5] += tb[i * 3 + 2];
        }
#pragma unroll
        for (int k = 0; k < 6; ++k)
            for (int off = 32; off > 0; off >>= 1)
                acc[k] += __shfl_down(acc[k], off, 64);
        __shared__ float red[4][6];
        if ((tid & 63) == 0)
#pragma unroll
            for (int k = 0; k < 6; ++k) red[tid >> 6][k] = acc[k];
        __syncthreads();
        if (tid == 0) {
            const float inv = 1.0f / (float)N_PTS;
            float l = 0.0f;
#pragma unroll
            for (int k = 0; k < 3; ++k) {
                float a = (red[0][k] + red[1][k] + red[2][k] + red[3][k]) * inv;
                float b = (red[0][k+3] + red[1][k+3] + red[2][k+3] + red[3][k+3]) * inv;
                l += sl1(a - b);
            }
            atomicAdd(&out[1], l * (1.0f / (B_VAL * 3.0f)));
        }
        return;
    }

    // ---- chamfer merge path ----
    const int n = chunk * BLOCK + tid;
    const float* psrc = (dir == 0) ? (X + (size_t)set * N_PTS * 3)
                                   : (T + (size_t)set * N_PTS * 3);
    const float* csrc = (dir == 0) ? (T + (size_t)set * N_PTS * 3)
                                   : (X + (size_t)set * N_PTS * 3);

    // Merge per-seg partials; ascending seg + strict < == lowest-index tiebreak.
    const float2* wq = ws + ((size_t)((set * 2 + dir) * SEGS) << 11);
    float bestd = INFINITY;
    unsigned int idx = 0;
#pragma unroll
    for (int s = 0; s < SEGS; ++s) {
        float2 v = wq[((size_t)s << 11) + n];
        if (v.x < bestd) { bestd = v.x; idx = __float_as_uint(v.y); }
    }

    float s = sl1(psrc[n * 3 + 0] - csrc[idx * 3 + 0])
            + sl1(psrc[n * 3 + 1] - csrc[idx * 3 + 1])
            + sl1(psrc[n * 3 + 2] - csrc[idx * 3 + 2]);

    __shared__ float wpart[4];
    for (int off = 32; off > 0; off >>= 1)
        s += __shfl_down(s, off, 64);
    if ((tid & 63) == 0) wpart[tid >> 6] = s;
    __syncthreads();
    if (tid == 0) {
        float tot = wpart[0] + wpart[1] + wpart[2] + wpart[3];
        atomicAdd(&out[0], W[set] * tot * (1.0f / (N_PTS * 3.0f * B_VAL)));
    }
}

extern "C" void kernel_launch(void* const* d_in, const int* in_sizes, int n_in,
                              void* d_out, int out_size, void* d_ws, size_t ws_size,
                              hipStream_t stream) {
    const float* X = (const float*)d_in[0];
    const float* T = (const float*)d_in[1];
    const float* W = (const float*)d_in[2];
    float* out = (float*)d_out;
    float2* ws = (float2*)d_ws;   // 32 * 16 * 2048 float2 = 8 MB

    chamfer_partial<<<dim3(SEGS, N_SETS, 2), BLOCK, 0, stream>>>(X, T, ws, out);
    finalize_kernel<<<dim3(N_PTS / BLOCK + 1, N_SETS, 2), BLOCK, 0, stream>>>(X, T, W, ws, out);
}